// Round 1
// 2399.448 us; speedup vs baseline: 1.2108x; 1.2108x over previous
//
#include <hip/hip_runtime.h>
#include <hip/hip_bf16.h>

typedef _Float16 f16;
typedef f16 f16x4 __attribute__((ext_vector_type(4)));
typedef f16 f16x8 __attribute__((ext_vector_type(8)));
typedef float f32x4 __attribute__((ext_vector_type(4)));

#define MFMA __builtin_amdgcn_mfma_f32_16x16x32_f16

constexpr int Bsz = 256, T = 512, D = 128, H = 512, C = 128;
constexpr int ROWS = 16;          // batch rows per workgroup (MFMA M)
constexpr int LDH = H + 8;        // LDS leading dim pad
constexpr int LDX = D + 8;
constexpr int TPB = 512;          // 8 waves
constexpr int NTG = H / 16;       // 32 n-tiles across H
constexpr int PKT = 8;            // persistent Whh k-tiles in VGPRs (128 VGPRs/wave)

// Pack fp32 [K][N] row-major -> fp16 MFMA-fragment order (unchanged, verified).
__global__ void pack_w(const float* __restrict__ W, int K, int N, f16* __restrict__ out) {
    int total = K * N;
    int NT = N / 16;
    for (int idx = blockIdx.x * blockDim.x + threadIdx.x; idx < total;
         idx += gridDim.x * blockDim.x) {
        int e    = idx & 7;
        int lane = (idx >> 3) & 63;
        int tile = idx >> 9;
        int kt = tile / NT, nt = tile % NT;
        int k = kt * 32 + 4 * (lane >> 4) + (e & 3) + 16 * (e >> 2);
        int n = nt * 16 + (lane & 15);
        out[idx] = (f16)W[(size_t)k * N + n];
    }
}

__device__ __forceinline__ f16x8 load_a(const f16* base, int ld, int kt, int l15, int l4) {
    const f16* p = base + l15 * ld + kt * 32 + 4 * l4;
    f16x4 lo = *(const f16x4*)p;
    f16x4 hi = *(const f16x4*)(p + 16);
    f16x8 r = {lo[0], lo[1], lo[2], lo[3], hi[0], hi[1], hi[2], hi[3]};
    return r;
}

__device__ __forceinline__ float fast_tanh(float v) {
    v = fminf(fmaxf(v, -8.f), 8.f);
    float e = __expf(2.f * v);
    return __fdividef(e - 1.f, e + 1.f);
}

// xproj[t][btile][ntg][lane][r] (f32, MFMA C-fragment order) = x_t @ Whx + bh.
// Fully parallel over (btile, t-chunk): uses all CUs, runs once.
__global__ __launch_bounds__(TPB, 2) void xproj_k(
    const float* __restrict__ x, const f16* __restrict__ wpack,
    const float* __restrict__ bh, float* __restrict__ xp) {
    const f16* Whx_p = wpack;
    __shared__ f16 xb[2][ROWS][LDX];
    const int tid = threadIdx.x, lane = tid & 63, w = tid >> 6;
    const int l15 = lane & 15, l4 = lane >> 4;
    const int bt = blockIdx.x;           // 0..15
    const int t0 = blockIdx.y * 16;      // 32 chunks of 16 timesteps
    const int b0 = bt * ROWS;
    const int xrow = tid >> 5, xd0 = (tid & 31) * 4;
    const int ntg0 = w * 4;

    float bh4[4];
#pragma unroll
    for (int nt = 0; nt < 4; nt++) bh4[nt] = bh[(ntg0 + nt) * 16 + l15];
    {
        float4 v = *(const float4*)&x[((size_t)(b0 + xrow) * T + t0) * D + xd0];
        f16x4 h4 = {(f16)v.x, (f16)v.y, (f16)v.z, (f16)v.w};
        *(f16x4*)&xb[0][xrow][xd0] = h4;
    }
    __syncthreads();

    int p = 0;
    for (int tt = 0; tt < 16; tt++) {
        int t = t0 + tt;
        float4 xv;
        const bool havex = (tt + 1 < 16);
        if (havex)
            xv = *(const float4*)&x[((size_t)(b0 + xrow) * T + (t + 1)) * D + xd0];
        f32x4 acc[4];
#pragma unroll
        for (int nt = 0; nt < 4; nt++)
            acc[nt] = (f32x4){bh4[nt], bh4[nt], bh4[nt], bh4[nt]};
#pragma unroll
        for (int kt = 0; kt < D / 32; kt++) {
            f16x8 a = load_a(&xb[p][0][0], LDX, kt, l15, l4);
            const f16* btp = Whx_p + (((size_t)kt * NTG + ntg0) * 64 + lane) * 8;
#pragma unroll
            for (int nt = 0; nt < 4; nt++) {
                f16x8 b = *(const f16x8*)(btp + (size_t)nt * 512);
                acc[nt] = MFMA(a, b, acc[nt], 0, 0, 0);
            }
        }
        if (havex) {
            f16x4 h4 = {(f16)xv.x, (f16)xv.y, (f16)xv.z, (f16)xv.w};
            *(f16x4*)&xb[p ^ 1][xrow][xd0] = h4;
        }
        float* op = xp + ((((size_t)t * 16 + bt) * NTG + ntg0) * 64 + lane) * 4;
#pragma unroll
        for (int nt = 0; nt < 4; nt++) *(f32x4*)(op + nt * 256) = acc[nt];
        __syncthreads();
        p ^= 1;
    }
}

// XP=1: xproj precomputed (fast). XP=0: in-loop Whx fallback if ws too small.
template <int XP>
__global__ __launch_bounds__(TPB, 2) void rnn_main(
    const float* __restrict__ x, const f16* __restrict__ wpack,
    const float* __restrict__ xproj, const float* __restrict__ bh,
    const float* __restrict__ bp, float* __restrict__ out) {
    const f16* Whx_p = wpack;
    const f16* Whh_p = wpack + D * H;
    const f16* Wph_p = wpack + D * H + H * H;

    __shared__ f16 hbuf[2][ROWS][LDH];
    __shared__ f16 xbuf[2][ROWS][LDX];   // only touched when XP==0

    const int tid = threadIdx.x, lane = tid & 63, w = tid >> 6;
    const int l15 = lane & 15, l4 = lane >> 4;
    const int b0 = blockIdx.x * ROWS;
    const int xrow = tid >> 5, xd0 = (tid & 31) * 4;
    const int ntg0 = w * 4;

    // Persistent half of Whh: k-tiles 0..7 of this wave's 64-col strip (128 VGPRs).
    f16x8 wreg[PKT][4];
#pragma unroll
    for (int kt = 0; kt < PKT; kt++)
#pragma unroll
        for (int nt = 0; nt < 4; nt++)
            wreg[kt][nt] =
                *(const f16x8*)(Whh_p + (((size_t)kt * NTG + ntg0 + nt) * 64 + lane) * 8);

    for (int i = tid; i < ROWS * LDH; i += TPB) (&hbuf[0][0][0])[i] = (f16)0.f;

    float bh4[4];
    f32x4 xpn[4];
    const float* xprow = nullptr;
    if constexpr (XP) {
        xprow = xproj + (((size_t)blockIdx.x * NTG + ntg0) * 64 + lane) * 4;
#pragma unroll
        for (int nt = 0; nt < 4; nt++) xpn[nt] = *(const f32x4*)(xprow + nt * 256);
    } else {
#pragma unroll
        for (int nt = 0; nt < 4; nt++) bh4[nt] = bh[(ntg0 + nt) * 16 + l15];
        float4 v = *(const float4*)&x[((size_t)(b0 + xrow) * T + 0) * D + xd0];
        f16x4 h4 = {(f16)v.x, (f16)v.y, (f16)v.z, (f16)v.w};
        *(f16x4*)&xbuf[0][xrow][xd0] = h4;
    }
    __syncthreads();

    int p = 0;
    for (int t = 0; t < T; t++) {
        f32x4 acc[4];
        f32x4 xpn2[4];
        if constexpr (XP) {
#pragma unroll
            for (int nt = 0; nt < 4; nt++) acc[nt] = xpn[nt];
            // prefetch next step's xproj fragments (lands under this step's MFMAs)
            const float* q =
                xprow + (size_t)(t + 1 < T ? t + 1 : t) * (16 * NTG * 64 * 4);
#pragma unroll
            for (int nt = 0; nt < 4; nt++) xpn2[nt] = *(const f32x4*)(q + nt * 256);
        } else {
#pragma unroll
            for (int nt = 0; nt < 4; nt++)
                acc[nt] = (f32x4){bh4[nt], bh4[nt], bh4[nt], bh4[nt]};
        }

        const f16* hb = &hbuf[p][0][0];

        if constexpr (!XP) {
            float4 xv;
            const bool havex = (t + 1 < T);
            if (havex)
                xv = *(const float4*)&x[((size_t)(b0 + xrow) * T + (t + 1)) * D + xd0];
            // opaque base: stop LICM hoisting loop-invariant weight loads
            uintptr_t wxu = (uintptr_t)Whx_p;
            asm volatile("" : "+s"(wxu));
            const f16* wxs = (const f16*)wxu;
#pragma unroll
            for (int kt = 0; kt < D / 32; kt++) {
                f16x8 a = load_a(&xbuf[p][0][0], LDX, kt, l15, l4);
                const f16* bt = wxs + (((size_t)kt * NTG + ntg0) * 64 + lane) * 8;
#pragma unroll
                for (int nt = 0; nt < 4; nt++) {
                    f16x8 b = *(const f16x8*)(bt + (size_t)nt * 512);
                    acc[nt] = MFMA(a, b, acc[nt], 0, 0, 0);
                }
            }
            if (havex) {
                f16x4 h4 = {(f16)xv.x, (f16)xv.y, (f16)xv.z, (f16)xv.w};
                *(f16x4*)&xbuf[p ^ 1][xrow][xd0] = h4;
            }
        }

        // ---- h @ Whh: persistent kt 0..7 (VGPR) interleaved with streamed kt 8..15 ----
        uintptr_t whu = (uintptr_t)Whh_p;
        asm volatile("" : "+s"(whu));   // fresh loads every step (no LICM blowup)
        const f16* wbase = (const f16*)whu + ((size_t)ntg0 * 64 + lane) * 8;

        f16x8 sA[4], sB[4];
        auto LS = [&](int kt, f16x8(&bf)[4]) {
#pragma unroll
            for (int nt = 0; nt < 4; nt++)
                bf[nt] = *(const f16x8*)(wbase + ((size_t)kt * NTG + nt) * 512);
        };
        auto PK = [&](int kt) {
            f16x8 a = load_a(hb, LDH, kt, l15, l4);
#pragma unroll
            for (int nt = 0; nt < 4; nt++)
                acc[nt] = MFMA(a, wreg[kt][nt], acc[nt], 0, 0, 0);
        };
        auto CS = [&](int kt, f16x8(&bf)[4]) {
            f16x8 a = load_a(hb, LDH, kt, l15, l4);
#pragma unroll
            for (int nt = 0; nt < 4; nt++) acc[nt] = MFMA(a, bf[nt], acc[nt], 0, 0, 0);
        };

        LS(8, sA);
        LS(9, sB);
        PK(0); CS(8, sA);  LS(10, sA);
        PK(1); CS(9, sB);  LS(11, sB);
        PK(2); CS(10, sA); LS(12, sA);
        PK(3); CS(11, sB); LS(13, sB);
        PK(4); CS(12, sA); LS(14, sA);
        PK(5); CS(13, sB); LS(15, sB);
        PK(6); CS(14, sA);
        PK(7); CS(15, sB);

        // h_new = tanh(acc); C/D layout: col = lane&15, row = 4*(lane>>4)+r
#pragma unroll
        for (int nt = 0; nt < 4; nt++)
#pragma unroll
            for (int r = 0; r < 4; r++) {
                float th = fast_tanh(acc[nt][r]);
                hbuf[p ^ 1][l4 * 4 + r][(ntg0 + nt) * 16 + l15] = (f16)th;
            }
        if constexpr (XP) {
#pragma unroll
            for (int nt = 0; nt < 4; nt++) xpn[nt] = xpn2[nt];
        }
        __syncthreads();
        p ^= 1;
    }

    // out = h_T @ Wph + bp ; wave w owns output cols [w*16, w*16+16)
    {
        float bpv = bp[w * 16 + l15];
        f32x4 acc = {bpv, bpv, bpv, bpv};
#pragma unroll 4
        for (int kt = 0; kt < H / 32; kt++) {
            f16x8 a = load_a(&hbuf[p][0][0], LDH, kt, l15, l4);
            f16x8 b = *(const f16x8*)(Wph_p + (((size_t)kt * (C / 16) + w) * 64 + lane) * 8);
            acc = MFMA(a, b, acc, 0, 0, 0);
        }
#pragma unroll
        for (int r = 0; r < 4; r++)
            out[(size_t)(b0 + l4 * 4 + r) * C + w * 16 + l15] = acc[r];
    }
}

extern "C" void kernel_launch(void* const* d_in, const int* in_sizes, int n_in,
                              void* d_out, int out_size, void* d_ws, size_t ws_size,
                              hipStream_t stream) {
    const float* x   = (const float*)d_in[0];
    const float* Whx = (const float*)d_in[1];
    const float* Whh = (const float*)d_in[2];
    const float* Wph = (const float*)d_in[3];
    const float* bh  = (const float*)d_in[4];
    const float* bp  = (const float*)d_in[5];

    f16* wp = (f16*)d_ws; // 768 KB packed fp16 weights
    pack_w<<<dim3(128), 256, 0, stream>>>(Whx, D, H, wp);
    pack_w<<<dim3(512), 256, 0, stream>>>(Whh, H, H, wp + D * H);
    pack_w<<<dim3(128), 256, 0, stream>>>(Wph, H, C, wp + D * H + H * H);

    const size_t wbytes  = (size_t)(D * H + H * H + H * C) * sizeof(f16); // 768 KB
    const size_t xpbytes = (size_t)T * (Bsz / ROWS) * NTG * 64 * 4 * sizeof(float); // 256 MB

    if (ws_size >= wbytes + xpbytes) {
        float* xpb = (float*)((char*)d_ws + wbytes);
        xproj_k<<<dim3(Bsz / ROWS, T / 16), TPB, 0, stream>>>(x, wp, bh, xpb);
        rnn_main<1><<<dim3(Bsz / ROWS), TPB, 0, stream>>>(x, wp, xpb, bh, bp,
                                                          (float*)d_out);
    } else {
        rnn_main<0><<<dim3(Bsz / ROWS), TPB, 0, stream>>>(x, wp, nullptr, bh, bp,
                                                          (float*)d_out);
    }
}

// Round 2
// 1822.136 us; speedup vs baseline: 1.5944x; 1.3168x over previous
//
#include <hip/hip_runtime.h>
#include <hip/hip_bf16.h>
#include <type_traits>

typedef _Float16 f16;
typedef f16 f16x4 __attribute__((ext_vector_type(4)));
typedef f16 f16x8 __attribute__((ext_vector_type(8)));
typedef float f32x4 __attribute__((ext_vector_type(4)));

#define MFMA __builtin_amdgcn_mfma_f32_16x16x32_f16

constexpr int Bsz = 256, T = 512, D = 128, H = 512, C = 128;
constexpr int ROWS = 16;          // batch rows per workgroup (MFMA M)
constexpr int LDH = H + 8;        // LDS leading dim pad
constexpr int LDX = D + 8;
constexpr int TPB = 512;          // 8 waves
constexpr int NTG = H / 16;       // 32 n-tiles across H
constexpr int PKT = 8;            // Whh k-tiles pinned in regs (kt 0..7)
constexpr int KTL = 3;            // Whh k-tiles staged in LDS (kt 8..10)
// Whh kt 11..15 streamed from L2 each step.

// xproj element stride per timestep: [t][bt(16)][tile(32)][lane(64)][4]
constexpr size_t XSTRIDE = (size_t)16 * NTG * 256;

// Pack fp32 [K][N] row-major -> fp16 MFMA-fragment order (verified).
__global__ void pack_w(const float* __restrict__ W, int K, int N, f16* __restrict__ out) {
    int total = K * N;
    int NT = N / 16;
    for (int idx = blockIdx.x * blockDim.x + threadIdx.x; idx < total;
         idx += gridDim.x * blockDim.x) {
        int e    = idx & 7;
        int lane = (idx >> 3) & 63;
        int tile = idx >> 9;
        int kt = tile / NT, nt = tile % NT;
        int k = kt * 32 + 4 * (lane >> 4) + (e & 3) + 16 * (e >> 2);
        int n = nt * 16 + (lane & 15);
        out[idx] = (f16)W[(size_t)k * N + n];
    }
}

__device__ __forceinline__ f16x8 load_a(const f16* base, int ld, int kt, int l15, int l4) {
    const f16* p = base + l15 * ld + kt * 32 + 4 * l4;
    f16x4 lo = *(const f16x4*)p;
    f16x4 hi = *(const f16x4*)(p + 16);
    f16x8 r = {lo[0], lo[1], lo[2], lo[3], hi[0], hi[1], hi[2], hi[3]};
    return r;
}

__device__ __forceinline__ float fast_tanh(float v) {
    v = fminf(fmaxf(v, -8.f), 8.f);
    float e = __expf(2.f * v);
    return __fdividef(e - 1.f, e + 1.f);
}

// xproj = x_t @ Whx + bh, stored in MFMA C-fragment order (f32 or f16).
// Fully parallel over (btile, t-chunk): uses all CUs, runs once.
template <typename OT>
__global__ __launch_bounds__(TPB, 2) void xproj_k(
    const float* __restrict__ x, const f16* __restrict__ wpack,
    const float* __restrict__ bh, OT* __restrict__ xp) {
    const f16* Whx_p = wpack;
    __shared__ f16 xb[2][ROWS][LDX];
    const int tid = threadIdx.x, lane = tid & 63, w = tid >> 6;
    const int l15 = lane & 15, l4 = lane >> 4;
    const int bt = blockIdx.x;       // 0..15
    const int t0 = blockIdx.y * 16;  // chunks of 16 timesteps
    const int b0 = bt * ROWS;
    const int xrow = tid >> 5, xd0 = (tid & 31) * 4;
    const int ntg0 = w * 4;

    float bh4[4];
#pragma unroll
    for (int nt = 0; nt < 4; nt++) bh4[nt] = bh[(ntg0 + nt) * 16 + l15];
    {
        float4 v = *(const float4*)&x[((size_t)(b0 + xrow) * T + t0) * D + xd0];
        f16x4 h4 = {(f16)v.x, (f16)v.y, (f16)v.z, (f16)v.w};
        *(f16x4*)&xb[0][xrow][xd0] = h4;
    }
    __syncthreads();

    int p = 0;
    for (int tt = 0; tt < 16; tt++) {
        int t = t0 + tt;
        float4 xv;
        const bool havex = (tt + 1 < 16);
        if (havex)
            xv = *(const float4*)&x[((size_t)(b0 + xrow) * T + (t + 1)) * D + xd0];
        f32x4 acc[4];
#pragma unroll
        for (int nt = 0; nt < 4; nt++)
            acc[nt] = (f32x4){bh4[nt], bh4[nt], bh4[nt], bh4[nt]};
#pragma unroll
        for (int kt = 0; kt < D / 32; kt++) {
            f16x8 a = load_a(&xb[p][0][0], LDX, kt, l15, l4);
            const f16* btp = Whx_p + (((size_t)kt * NTG + ntg0) * 64 + lane) * 8;
#pragma unroll
            for (int nt = 0; nt < 4; nt++) {
                f16x8 b = *(const f16x8*)(btp + (size_t)nt * 512);
                acc[nt] = MFMA(a, b, acc[nt], 0, 0, 0);
            }
        }
        if (havex) {
            f16x4 h4 = {(f16)xv.x, (f16)xv.y, (f16)xv.z, (f16)xv.w};
            *(f16x4*)&xb[p ^ 1][xrow][xd0] = h4;
        }
        OT* op = xp + (((size_t)t * 16 + bt) * NTG + ntg0) * 256 + (size_t)lane * 4;
#pragma unroll
        for (int nt = 0; nt < 4; nt++) {
            if constexpr (std::is_same_v<OT, float>) {
                *(f32x4*)(op + (size_t)nt * 256) = acc[nt];
            } else {
                f16x4 v = {(f16)acc[nt][0], (f16)acc[nt][1], (f16)acc[nt][2],
                           (f16)acc[nt][3]};
                *(f16x4*)(op + (size_t)nt * 256) = v;
            }
        }
        __syncthreads();
        p ^= 1;
    }
}

// XP=1: f32 xproj. XP=2: f16 xproj. XP=0: in-loop Whx fallback.
template <int XP>
__global__ __launch_bounds__(TPB, 2) void rnn_main(
    const float* __restrict__ x, const f16* __restrict__ wpack,
    const void* __restrict__ xproj, const float* __restrict__ bh,
    const float* __restrict__ bp, float* __restrict__ out) {
    const f16* Whx_p = wpack;
    const f16* Whh_p = wpack + D * H;
    const f16* Wph_p = wpack + D * H + H * H;

    __shared__ f16 hbuf[2][ROWS][LDH];                       // 33.3 KB
    __shared__ f16 whh_lds[KTL * NTG * 64 * 8];              // 96 KB, kt 8..10
    __shared__ f16 xbuf[(XP == 0) ? 2 : 1][(XP == 0) ? ROWS : 1][(XP == 0) ? LDX : 1];

    const int tid = threadIdx.x, lane = tid & 63, w = tid >> 6;
    const int l15 = lane & 15, l4 = lane >> 4;
    const int b0 = blockIdx.x * ROWS;
    const int xrow = tid >> 5, xd0 = (tid & 31) * 4;
    const int ntg0 = w * 4;

    // Pinned Whh kt 0..7 of this wave's 64-col strip (128 regs, AGPR-resident).
    f16x8 wreg[PKT][4];
#pragma unroll
    for (int kt = 0; kt < PKT; kt++)
#pragma unroll
        for (int nt = 0; nt < 4; nt++)
            wreg[kt][nt] =
                *(const f16x8*)(Whh_p + (((size_t)kt * NTG + ntg0 + nt) * 64 + lane) * 8);

    // Stage Whh kt 8..10 into LDS (contiguous in pack order).
    {
        const f16* src = Whh_p + (size_t)PKT * NTG * 512;
        for (int i = tid; i < KTL * NTG * 64; i += TPB)
            *(f16x8*)&whh_lds[(size_t)i * 8] = *(const f16x8*)(src + (size_t)i * 8);
    }
    for (int i = tid; i < ROWS * LDH; i += TPB) (&hbuf[0][0][0])[i] = (f16)0.f;

    float bh4[4];
    const float* xpf = nullptr;
    const f16* xph = nullptr;
    if constexpr (XP == 1) {
        xpf = (const float*)xproj + (((size_t)blockIdx.x * NTG + ntg0) * 64 + lane) * 4;
    } else if constexpr (XP == 2) {
        xph = (const f16*)xproj + (((size_t)blockIdx.x * NTG + ntg0) * 64 + lane) * 4;
    } else {
#pragma unroll
        for (int nt = 0; nt < 4; nt++) bh4[nt] = bh[(ntg0 + nt) * 16 + l15];
        float4 v = *(const float4*)&x[((size_t)(b0 + xrow) * T + 0) * D + xd0];
        f16x4 h4 = {(f16)v.x, (f16)v.y, (f16)v.z, (f16)v.w};
        *(f16x4*)&xbuf[0][xrow][xd0] = h4;
    }

    // Prologue: preload streamed kt 11,12 (addresses are loop-invariant).
    f16x8 sA[4], sB[4];
    {
        const f16* wb0 = Whh_p + ((size_t)ntg0 * 64 + lane) * 8;
#pragma unroll
        for (int nt = 0; nt < 4; nt++)
            sA[nt] = *(const f16x8*)(wb0 + ((size_t)11 * NTG + nt) * 512);
#pragma unroll
        for (int nt = 0; nt < 4; nt++)
            sB[nt] = *(const f16x8*)(wb0 + ((size_t)12 * NTG + nt) * 512);
    }
    __syncthreads();

    int p = 0;
    for (int t = 0; t < T; t++) {
        // opaque per-iter handles: defeat LICM on loop-invariant weight loads
        uintptr_t whu = (uintptr_t)Whh_p;
        asm volatile("" : "+s"(whu));
        const f16* wbase = (const f16*)whu + ((size_t)ntg0 * 64 + lane) * 8;
        int zoff = 0;
        asm volatile("" : "+v"(zoff));

        // issue this step's xproj fragment loads (consumed after MFMA section)
        f32x4 xr32[4];
        f16x4 xr16[4];
        if constexpr (XP == 1) {
            const float* xq = xpf + (size_t)t * XSTRIDE;
#pragma unroll
            for (int nt = 0; nt < 4; nt++) xr32[nt] = *(const f32x4*)(xq + (size_t)nt * 256);
        } else if constexpr (XP == 2) {
            const f16* xq = xph + (size_t)t * XSTRIDE;
#pragma unroll
            for (int nt = 0; nt < 4; nt++) xr16[nt] = *(const f16x4*)(xq + (size_t)nt * 256);
        }

        f32x4 acc[4];
        if constexpr (XP == 0) {
#pragma unroll
            for (int nt = 0; nt < 4; nt++)
                acc[nt] = (f32x4){bh4[nt], bh4[nt], bh4[nt], bh4[nt]};
        } else {
#pragma unroll
            for (int nt = 0; nt < 4; nt++) acc[nt] = (f32x4){0.f, 0.f, 0.f, 0.f};
        }

        const f16* hb = &hbuf[p][0][0];

        if constexpr (XP == 0) {
            float4 xv;
            const bool havex = (t + 1 < T);
            if (havex)
                xv = *(const float4*)&x[((size_t)(b0 + xrow) * T + (t + 1)) * D + xd0];
            uintptr_t wxu = (uintptr_t)Whx_p;
            asm volatile("" : "+s"(wxu));
            const f16* wxs = (const f16*)wxu;
#pragma unroll
            for (int kt = 0; kt < D / 32; kt++) {
                f16x8 a = load_a(&xbuf[p][0][0], LDX, kt, l15, l4);
                const f16* bt = wxs + (((size_t)kt * NTG + ntg0) * 64 + lane) * 8;
#pragma unroll
                for (int nt = 0; nt < 4; nt++) {
                    f16x8 b = *(const f16x8*)(bt + (size_t)nt * 512);
                    acc[nt] = MFMA(a, b, acc[nt], 0, 0, 0);
                }
            }
            if (havex) {
                f16x4 h4 = {(f16)xv.x, (f16)xv.y, (f16)xv.z, (f16)xv.w};
                *(f16x4*)&xbuf[p ^ 1][xrow][xd0] = h4;
            }
        }

        // ---- h @ Whh: pinned kt0..7 (regs) | LDS kt8..10 | streamed kt11..15 ----
        auto LS = [&](int kt, f16x8(&bf)[4]) {
#pragma unroll
            for (int nt = 0; nt < 4; nt++)
                bf[nt] = *(const f16x8*)(wbase + ((size_t)kt * NTG + nt) * 512);
        };
        auto PK = [&](int kt) {
            f16x8 a = load_a(hb, LDH, kt, l15, l4);
#pragma unroll
            for (int nt = 0; nt < 4; nt++)
                acc[nt] = MFMA(a, wreg[kt][nt], acc[nt], 0, 0, 0);
        };
        auto CL = [&](int ktl) {
            f16x8 a = load_a(hb, LDH, PKT + ktl, l15, l4);
#pragma unroll
            for (int nt = 0; nt < 4; nt++) {
                f16x8 b = *(const f16x8*)&whh_lds[(((size_t)ktl * NTG + ntg0 + nt) * 64 +
                                                   lane) * 8 + zoff];
                acc[nt] = MFMA(a, b, acc[nt], 0, 0, 0);
            }
        };
        auto CS = [&](int kt, f16x8(&bf)[4]) {
            f16x8 a = load_a(hb, LDH, kt, l15, l4);
#pragma unroll
            for (int nt = 0; nt < 4; nt++) acc[nt] = MFMA(a, bf[nt], acc[nt], 0, 0, 0);
        };

        PK(0); CL(0);
        PK(1); CL(1);
        PK(2); CL(2);
        PK(3); CS(11, sA); LS(13, sA);
        PK(4); CS(12, sB); LS(14, sB);
        PK(5); CS(13, sA); LS(15, sA);
        PK(6); CS(14, sB);
        PK(7); CS(15, sA);
        // hoist next step's kt11/12 loads across the barrier (invariant addresses)
        LS(11, sA); LS(12, sB);

        // h_new = tanh(acc [+ xproj]); C/D layout: col=lane&15, row=4*(lane>>4)+r
#pragma unroll
        for (int nt = 0; nt < 4; nt++)
#pragma unroll
            for (int r = 0; r < 4; r++) {
                float v = acc[nt][r];
                if constexpr (XP == 1) v += xr32[nt][r];
                else if constexpr (XP == 2) v += (float)xr16[nt][r];
                float th = fast_tanh(v);
                hbuf[p ^ 1][l4 * 4 + r][(ntg0 + nt) * 16 + l15] = (f16)th;
            }
        __syncthreads();
        p ^= 1;
    }

    // out = h_T @ Wph + bp ; wave w owns output cols [w*16, w*16+16)
    {
        float bpv = bp[w * 16 + l15];
        f32x4 acc = {bpv, bpv, bpv, bpv};
#pragma unroll 4
        for (int kt = 0; kt < H / 32; kt++) {
            f16x8 a = load_a(&hbuf[p][0][0], LDH, kt, l15, l4);
            f16x8 b = *(const f16x8*)(Wph_p + (((size_t)kt * (C / 16) + w) * 64 + lane) * 8);
            acc = MFMA(a, b, acc, 0, 0, 0);
        }
#pragma unroll
        for (int r = 0; r < 4; r++)
            out[(size_t)(b0 + l4 * 4 + r) * C + w * 16 + l15] = acc[r];
    }
}

extern "C" void kernel_launch(void* const* d_in, const int* in_sizes, int n_in,
                              void* d_out, int out_size, void* d_ws, size_t ws_size,
                              hipStream_t stream) {
    const float* x   = (const float*)d_in[0];
    const float* Whx = (const float*)d_in[1];
    const float* Whh = (const float*)d_in[2];
    const float* Wph = (const float*)d_in[3];
    const float* bh  = (const float*)d_in[4];
    const float* bp  = (const float*)d_in[5];

    f16* wp = (f16*)d_ws; // 768 KB packed fp16 weights
    pack_w<<<dim3(128), 256, 0, stream>>>(Whx, D, H, wp);
    pack_w<<<dim3(512), 256, 0, stream>>>(Whh, H, H, wp + D * H);
    pack_w<<<dim3(128), 256, 0, stream>>>(Wph, H, C, wp + D * H + H * H);

    const size_t wbytes = (size_t)(D * H + H * H + H * C) * sizeof(f16); // 768 KB
    const size_t xpel   = (size_t)T * 16 * NTG * 256;                    // 67.1M elems

    if (ws_size >= wbytes + xpel * sizeof(float)) {        // 257 MB: f32 xproj
        float* xpb = (float*)((char*)d_ws + wbytes);
        xproj_k<float><<<dim3(16, T / 16), TPB, 0, stream>>>(x, wp, bh, xpb);
        rnn_main<1><<<dim3(Bsz / ROWS), TPB, 0, stream>>>(x, wp, xpb, bh, bp,
                                                          (float*)d_out);
    } else if (ws_size >= wbytes + xpel * sizeof(f16)) {   // 129 MB: f16 xproj
        f16* xpb = (f16*)((char*)d_ws + wbytes);
        xproj_k<f16><<<dim3(16, T / 16), TPB, 0, stream>>>(x, wp, bh, xpb);
        rnn_main<2><<<dim3(Bsz / ROWS), TPB, 0, stream>>>(x, wp, xpb, bh, bp,
                                                          (float*)d_out);
    } else {                                               // fallback: in-loop Whx
        rnn_main<0><<<dim3(Bsz / ROWS), TPB, 0, stream>>>(x, wp, nullptr, bh, bp,
                                                          (float*)d_out);
    }
}